// Round 11
// baseline (251.637 us; speedup 1.0000x reference)
//
#include <hip/hip_runtime.h>

#define S_LEN 4096
#define DHEAD 64
#define BK    64       // K/V rows per tile
#define NT    (S_LEN / BK)
#define TILE_HALFS (BK * DHEAD)   // 4096 halfs / floats per tile

typedef __fp16   pk16x2 __attribute__((ext_vector_type(2)));
typedef _Float16 half8  __attribute__((ext_vector_type(8)));
typedef float    f32x16 __attribute__((ext_vector_type(16)));
typedef unsigned uint2v __attribute__((ext_vector_type(2)));

#define MFMA32(a, b, c) __builtin_amdgcn_mfma_f32_32x32x16_f16(a, b, c, 0, 0, 0)

__device__ __forceinline__ unsigned pk2u(float a, float b) {
    union { pk16x2 p; unsigned u; } x;
    x.p = __builtin_amdgcn_cvt_pkrtz(a, b);
    return x.u;
}

// permlane32_swap(x,y): r.x[l] = l<32 ? x[l] : y[l-32] ; r.y[l] = l<32 ? x[l+32] : y[l]
__device__ __forceinline__ uint2v pls(unsigned x, unsigned y) {
    return __builtin_amdgcn_permlane32_swap(x, y, false, false);
}
__device__ __forceinline__ float xmax32(float v) {
    uint2v r = pls(__float_as_uint(v), __float_as_uint(v));
    return fmaxf(__uint_as_float(r.x), __uint_as_float(r.y));
}
__device__ __forceinline__ float xadd32(float v) {
    uint2v r = pls(__float_as_uint(v), __float_as_uint(v));
    return __uint_as_float(r.x) + __uint_as_float(r.y);
}

// ---------------------------------------------------------------------------
// Pass 1: is the mask anywhere nonzero? 2048x256 threads, 8 float4/thread.
// ---------------------------------------------------------------------------
__global__ void mask_flag_kernel(const float4* __restrict__ mask, int* __restrict__ flag) {
    const long stride = 2048L * 256;
    long i = (long)blockIdx.x * 256 + threadIdx.x;
    int nz = 0;
    #pragma unroll
    for (int it = 0; it < 8; ++it) {
        float4 a = mask[i + it * stride];
        nz |= (a.x != 0.f) | (a.y != 0.f) | (a.z != 0.f) | (a.w != 0.f);
    }
    if (__any(nz)) {
        if ((threadIdx.x & 63) == 0) atomicOr(flag, 1);
    }
}

// ---------------------------------------------------------------------------
// Pass 2: flash attention. r10 champion (32x32 MFMA, in-register P via
// permlane32_swap, inline fp32 staging, XCD-chunked decode) with TILE-PAIR
// BATCHING: 4-ring LDS buffers, two K-tiles per iteration sharing ONE joint
// softmax (one max-merge / need-check / rescale / xadd32 per 128 k-rows) and
// ONE barrier per 2 tiles (64 -> 32). All layouts/swizzles byte-identical to
// the r10-verified kernel. LDS 64 KB -> 2 blocks/CU (grid-capped anyway).
//   KT[r][chunk c] = K[r][8*(c ^ (r&7)) .. +8]
//   VT[d][chunk c] = V[8*(c ^ (d&7) ^ ((d>>3)&7)) + j][d]
// ---------------------------------------------------------------------------
__global__ __launch_bounds__(256, 2) void attn32p_kernel(
    const float* __restrict__ Q, const float* __restrict__ K,
    const float* __restrict__ V, const int* __restrict__ dkp,
    const float* __restrict__ mask, const int* __restrict__ maskflag,
    float* __restrict__ O)
{
    const int bid = blockIdx.x;
    const int L   = (bid & 7) * 64 + (bid >> 3);   // XCD-chunked decode, 512 blocks
    const int bh  = L >> 5;                         // 0..15
    const int qt  = L & 31;                         // 0..31

    const int tid  = threadIdx.x;
    const int w    = tid >> 6;          // wave 0..3
    const int lane = tid & 63;
    const int l31  = lane & 31;
    const int h    = lane >> 5;
    const int cx   = lane & 7;                       // K read key (row l31)
    const int vkey = (l31 ^ (l31 >> 3)) & 7;         // V read key (row l31)

    const long gbase = (long)bh * S_LEN * DHEAD;
    const float* Qh = Q + gbase;
    const float* Kh = K + gbase;
    const float* Vh = V + gbase;

    const int q0 = qt * 128 + w * 32;               // this wave's 32 q-rows
    const float csq  = rsqrtf((float)dkp[0]) * 1.44269504088896f;
    const float mfac = -1e9f * 1.44269504088896f;
    const bool use_mask = (maskflag[0] != 0);

    __shared__ __align__(16) _Float16 KT[4][TILE_HALFS];   // 32 KB (4-ring)
    __shared__ __align__(16) _Float16 VT[4][TILE_HALFS];   // 32 KB (4-ring)

    // ---- Q B-operand frags, pre-scaled (lane -> Q[q0+l31][ks*16+8h+j]) ----
    half8 qf[4];
    #pragma unroll
    for (int ks = 0; ks < 4; ++ks) {
        const float4* src = (const float4*)(Qh + (long)(q0 + l31) * DHEAD + ks * 16 + h * 8);
        float4 a = src[0], b = src[1];
        union { unsigned u[4]; half8 h8; } u;
        u.u[0] = pk2u(a.x * csq, a.y * csq);
        u.u[1] = pk2u(a.z * csq, a.w * csq);
        u.u[2] = pk2u(b.x * csq, b.y * csq);
        u.u[3] = pk2u(b.z * csq, b.w * csq);
        qf[ks] = u.h8;
    }

    // ---- staging roles (r10-verified layouts) ----
    const int kr  = tid >> 2;            // K row 0..63
    const int ks4 = tid & 3;             // K 16-float segment
    const int vrp = tid >> 3;            // V row-pair 0..31
    const int vdq = tid & 7;             // V d-octet 0..7
    const float* Kb = Kh + (long)kr * DHEAD + ks4 * 16;
    const float* Vb = Vh + (long)(2 * vrp) * DHEAD + vdq * 8;
    const int kcol0 = (((2 * ks4)     ^ (kr & 7)) << 3);
    const int kcol1 = (((2 * ks4 + 1) ^ (kr & 7)) << 3);
    const int vd0   = vdq * 8;
    const int voct  = vrp >> 2;          // V row-octet
    const int vlow  = (2 * vrp) & 7;     // position within chunk

    float4 kf[4], vf[4];
    auto load_tile = [&](int kt) {
        const float4* kp  = (const float4*)(Kb + (long)kt * TILE_HALFS);
        kf[0] = kp[0]; kf[1] = kp[1]; kf[2] = kp[2]; kf[3] = kp[3];
        const float4* vp0 = (const float4*)(Vb + (long)kt * TILE_HALFS);
        const float4* vp1 = (const float4*)(Vb + (long)kt * TILE_HALFS + DHEAD);
        vf[0] = vp0[0]; vf[1] = vp0[1]; vf[2] = vp1[0]; vf[3] = vp1[1];
    };
    auto store_tile = [&](int bb) {
        union { unsigned u[4]; half8 h8; } u0, u1;
        u0.u[0] = pk2u(kf[0].x, kf[0].y);
        u0.u[1] = pk2u(kf[0].z, kf[0].w);
        u0.u[2] = pk2u(kf[1].x, kf[1].y);
        u0.u[3] = pk2u(kf[1].z, kf[1].w);
        u1.u[0] = pk2u(kf[2].x, kf[2].y);
        u1.u[1] = pk2u(kf[2].z, kf[2].w);
        u1.u[2] = pk2u(kf[3].x, kf[3].y);
        u1.u[3] = pk2u(kf[3].z, kf[3].w);
        *(half8*)&KT[bb][kr * 64 + kcol0] = u0.h8;
        *(half8*)&KT[bb][kr * 64 + kcol1] = u1.h8;
        _Float16* vt = &VT[bb][0];
        #define VCOL(j) ((((voct ^ (j) ^ vdq) & 7) << 3) + vlow)
        *(pk16x2*)&vt[(vd0 + 0) * 64 + VCOL(0)] = __builtin_amdgcn_cvt_pkrtz(vf[0].x, vf[2].x);
        *(pk16x2*)&vt[(vd0 + 1) * 64 + VCOL(1)] = __builtin_amdgcn_cvt_pkrtz(vf[0].y, vf[2].y);
        *(pk16x2*)&vt[(vd0 + 2) * 64 + VCOL(2)] = __builtin_amdgcn_cvt_pkrtz(vf[0].z, vf[2].z);
        *(pk16x2*)&vt[(vd0 + 3) * 64 + VCOL(3)] = __builtin_amdgcn_cvt_pkrtz(vf[0].w, vf[2].w);
        *(pk16x2*)&vt[(vd0 + 4) * 64 + VCOL(4)] = __builtin_amdgcn_cvt_pkrtz(vf[1].x, vf[3].x);
        *(pk16x2*)&vt[(vd0 + 5) * 64 + VCOL(5)] = __builtin_amdgcn_cvt_pkrtz(vf[1].y, vf[3].y);
        *(pk16x2*)&vt[(vd0 + 6) * 64 + VCOL(6)] = __builtin_amdgcn_cvt_pkrtz(vf[1].z, vf[3].z);
        *(pk16x2*)&vt[(vd0 + 7) * 64 + VCOL(7)] = __builtin_amdgcn_cvt_pkrtz(vf[1].w, vf[3].w);
        #undef VCOL
    };

    // ---- QK / PV clusters (r10-verified bodies, buffer-parameterized) ----
    auto qk = [&](int bb, f32x16& sa, f32x16& sb) {
        __builtin_amdgcn_s_setprio(1);
        #pragma unroll
        for (int ks = 0; ks < 4; ++ks) {
            const int off = (((2 * ks + h) ^ cx) << 3);
            half8 a0 = *(const half8*)&KT[bb][(l31 << 6) + off];
            half8 a1 = *(const half8*)&KT[bb][2048 + (l31 << 6) + off];
            sa = MFMA32(a0, qf[ks], sa);
            sb = MFMA32(a1, qf[ks], sb);
        }
        __builtin_amdgcn_s_setprio(0);
    };

    f32x16 o0 = {0.f,0.f,0.f,0.f,0.f,0.f,0.f,0.f,0.f,0.f,0.f,0.f,0.f,0.f,0.f,0.f};
    f32x16 o1 = o0;
    float m_i = -INFINITY;
    float l_i = 0.0f;

    auto pv = [&](int bb, const f32x16& sa, const f32x16& sb) {
        unsigned wp[16];
        #pragma unroll
        for (int d = 0; d < 8; ++d) {
            wp[d]     = pk2u(sa[2*d], sa[2*d+1]);
            wp[8 + d] = pk2u(sb[2*d], sb[2*d+1]);
        }
        __builtin_amdgcn_s_setprio(1);
        #pragma unroll
        for (int si = 0; si < 4; ++si) {
            const int bs = (si >> 1) * 8 + (si & 1) * 4;
            uint2v r0 = pls(wp[bs + 0], wp[bs + 2]);
            uint2v r1 = pls(wp[bs + 1], wp[bs + 3]);
            union { unsigned u[4]; half8 h8; } pa;
            pa.u[0] = r0.x; pa.u[1] = r1.x; pa.u[2] = r0.y; pa.u[3] = r1.y;
            const int voff = (((2 * si + h) ^ vkey) << 3);
            half8 v0 = *(const half8*)&VT[bb][(l31 << 6) + voff];
            half8 v1 = *(const half8*)&VT[bb][2048 + (l31 << 6) + (voff ^ 32)];
            o0 = MFMA32(pa.h8, v0, o0);
            o1 = MFMA32(pa.h8, v1, o1);
        }
        __builtin_amdgcn_s_setprio(0);
    };

    // ---- prologue: stage tiles 0,1 into ring slots 0,1 ----
    load_tile(0); store_tile(0);
    load_tile(1); store_tile(1);
    __syncthreads();

    for (int kt = 0; kt < NT; kt += 2) {
        const int b0 = kt & 3, b1 = (kt + 1) & 3;

        // prefetch tile kt+2: load now, store right after QK(t0)
        if (kt + 2 < NT) load_tile(kt + 2);

        f32x16 s0 = {0.f,0.f,0.f,0.f,0.f,0.f,0.f,0.f,0.f,0.f,0.f,0.f,0.f,0.f,0.f,0.f};
        f32x16 s1 = s0, s2 = s0, s3 = s0;
        qk(b0, s0, s1);
        if (kt + 2 < NT) store_tile((kt + 2) & 3);

        // prefetch tile kt+3: latency hides under QK(t1)+softmax
        if (kt + 3 < NT) load_tile(kt + 3);
        qk(b1, s2, s3);

        if (use_mask) {
            const float* mrow = mask + (long)(q0 + l31) * S_LEN + kt * BK;
            #pragma unroll
            for (int r = 0; r < 16; ++r) {
                const int k = (r & 3) + ((r >> 2) << 3) + (h << 2);
                s0[r] += mfac * mrow[k];
                s1[r] += mfac * mrow[32 + k];
                s2[r] += mfac * mrow[BK + k];
                s3[r] += mfac * mrow[BK + 32 + k];
            }
        }

        // ---- joint online softmax over both tiles (ONE chain per pair) ----
        {
            float tt[16];
            #pragma unroll
            for (int i = 0; i < 8; ++i) {
                tt[i]     = fmaxf(fmaxf(s0[2*i], s0[2*i+1]), fmaxf(s1[2*i], s1[2*i+1]));
                tt[8 + i] = fmaxf(fmaxf(s2[2*i], s2[2*i+1]), fmaxf(s3[2*i], s3[2*i+1]));
            }
            #pragma unroll
            for (int i = 0; i < 8; ++i) tt[i] = fmaxf(tt[i], tt[8 + i]);
            float mx = fmaxf(fmaxf(fmaxf(tt[0], tt[1]), fmaxf(tt[2], tt[3])),
                             fmaxf(fmaxf(tt[4], tt[5]), fmaxf(tt[6], tt[7])));
            mx = xmax32(mx);                               // VALU, not DS
            const bool need = __any(mx > m_i + 8.0f);      // wave-uniform
            const float mnew = need ? fmaxf(m_i, mx) : m_i;
            float ra = 0.f, rb = 0.f;
            #pragma unroll
            for (int r = 0; r < 16; ++r) {
                float p0 = __builtin_amdgcn_exp2f(s0[r] - mnew);
                float p1 = __builtin_amdgcn_exp2f(s1[r] - mnew);
                float p2 = __builtin_amdgcn_exp2f(s2[r] - mnew);
                float p3 = __builtin_amdgcn_exp2f(s3[r] - mnew);
                s0[r] = p0; s1[r] = p1; s2[r] = p2; s3[r] = p3;
                ra += p0 + p1; rb += p2 + p3;
            }
            float rsum = xadd32(ra + rb);
            if (need) {
                const float alpha = __builtin_amdgcn_exp2f(m_i - mnew);
                #pragma unroll
                for (int r = 0; r < 16; ++r) {
                    const int qr = (r & 3) + ((r >> 2) << 3) + (h << 2);
                    float a_r = __shfl(alpha, qr, 64);
                    o0[r] *= a_r; o1[r] *= a_r;
                }
                l_i = alpha * l_i + rsum;
                m_i = mnew;
            } else {
                l_i += rsum;
            }
        }

        if (kt + 3 < NT) store_tile((kt + 3) & 3);

        // ---- O += P.V for both tiles (in-register P, pls direct) ----
        pv(b0, s0, s1);
        pv(b1, s2, s3);

        if (kt + 2 < NT) __syncthreads();    // one barrier per TILE PAIR
    }

    // ---- epilogue: O /= l (lane qr owns row qr's l) ----
    float* dst = O + gbase;
    #pragma unroll
    for (int r = 0; r < 16; ++r) {
        const int qr = (r & 3) + ((r >> 2) << 3) + (h << 2);
        float lq = __shfl(l_i, qr, 64);
        float inv = __builtin_amdgcn_rcpf(lq);
        const long row = (long)(q0 + qr) * DHEAD;
        dst[row + l31]      = o0[r] * inv;
        dst[row + 32 + l31] = o1[r] * inv;
    }
}

extern "C" void kernel_launch(void* const* d_in, const int* in_sizes, int n_in,
                              void* d_out, int out_size, void* d_ws, size_t ws_size,
                              hipStream_t stream) {
    const float* Q    = (const float*)d_in[0];
    const float* K    = (const float*)d_in[1];
    const float* V    = (const float*)d_in[2];
    const int*   dk   = (const int*)d_in[3];
    const float* mask = (const float*)d_in[4];
    float* out = (float*)d_out;
    int* flag = (int*)d_ws;

    (void)hipMemsetAsync(flag, 0, sizeof(int), stream);
    mask_flag_kernel<<<2048, 256, 0, stream>>>((const float4*)mask, flag);

    attn32p_kernel<<<512, 256, 0, stream>>>(Q, K, V, dk, mask, flag, out);
}

// Round 13
// 246.755 us; speedup vs baseline: 1.0198x; 1.0198x over previous
//
#include <hip/hip_runtime.h>

#define S_LEN 4096
#define DHEAD 64
#define BK    64       // K/V rows per tile
#define NT    (S_LEN / BK)
#define TILE_HALFS (BK * DHEAD)   // 4096 halfs / floats per tile

typedef __fp16   pk16x2 __attribute__((ext_vector_type(2)));
typedef _Float16 half8  __attribute__((ext_vector_type(8)));
typedef float    f32x16 __attribute__((ext_vector_type(16)));
typedef unsigned uint2v __attribute__((ext_vector_type(2)));

#define MFMA32(a, b, c) __builtin_amdgcn_mfma_f32_32x32x16_f16(a, b, c, 0, 0, 0)

__device__ __forceinline__ unsigned pk2u(float a, float b) {
    union { pk16x2 p; unsigned u; } x;
    x.p = __builtin_amdgcn_cvt_pkrtz(a, b);
    return x.u;
}

// permlane32_swap(x,y): r.x[l] = l<32 ? x[l] : y[l-32] ; r.y[l] = l<32 ? x[l+32] : y[l]
__device__ __forceinline__ uint2v pls(unsigned x, unsigned y) {
    return __builtin_amdgcn_permlane32_swap(x, y, false, false);
}
__device__ __forceinline__ float xmax32(float v) {
    uint2v r = pls(__float_as_uint(v), __float_as_uint(v));
    return fmaxf(__uint_as_float(r.x), __uint_as_float(r.y));
}
__device__ __forceinline__ float xadd32(float v) {
    uint2v r = pls(__float_as_uint(v), __float_as_uint(v));
    return __uint_as_float(r.x) + __uint_as_float(r.y);
}

// ---------------------------------------------------------------------------
// Pass 1: is the mask anywhere nonzero? 2048x256 threads, 8 float4/thread.
// ---------------------------------------------------------------------------
__global__ void mask_flag_kernel(const float4* __restrict__ mask, int* __restrict__ flag) {
    const long stride = 2048L * 256;
    long i = (long)blockIdx.x * 256 + threadIdx.x;
    int nz = 0;
    #pragma unroll
    for (int it = 0; it < 8; ++it) {
        float4 a = mask[i + it * stride];
        nz |= (a.x != 0.f) | (a.y != 0.f) | (a.z != 0.f) | (a.w != 0.f);
    }
    if (__any(nz)) {
        if ((threadIdx.x & 63) == 0) atomicOr(flag, 1);
    }
}

// ---------------------------------------------------------------------------
// Pass 2: flash attention. EXACT r10 champion per-tile bodies (32x32 MFMA,
// in-register P via permlane32_swap, THR=8 defer-max, inline fp32 staging,
// XCD-chunked decode) -- the ONLY change vs r10: 4-ring LDS slots + ONE
// barrier per 2 tiles (64 -> 32 barriers). s2/s3 never coexist with s0/s1,
// so register liveness stays at r10 levels (r11's joint-softmax VGPR blowup
// is avoided). Ring safety: iter reads slots {t,t+1}, writes {t+2,t+3} --
// disjoint mod 4 -> single end-of-pair barrier suffices.
//   KT[r][chunk c] = K[r][8*(c ^ (r&7)) .. +8]
//   VT[d][chunk c] = V[8*(c ^ (d&7) ^ ((d>>3)&7)) + j][d]
// (Resubmission of round-12 source: container failed twice on infra; kernel
// audit found no hang/fault capability -- no spins, no fences, LDS 64 KB,
// race-free ring. Identical code to keep the experiment's variable isolated.)
// ---------------------------------------------------------------------------
__global__ __launch_bounds__(256, 2) void attn32r_kernel(
    const float* __restrict__ Q, const float* __restrict__ K,
    const float* __restrict__ V, const int* __restrict__ dkp,
    const float* __restrict__ mask, const int* __restrict__ maskflag,
    float* __restrict__ O)
{
    const int bid = blockIdx.x;
    const int L   = (bid & 7) * 64 + (bid >> 3);   // XCD-chunked decode, 512 blocks
    const int bh  = L >> 5;                         // 0..15
    const int qt  = L & 31;                         // 0..31

    const int tid  = threadIdx.x;
    const int w    = tid >> 6;          // wave 0..3
    const int lane = tid & 63;
    const int l31  = lane & 31;
    const int h    = lane >> 5;
    const int cx   = lane & 7;                       // K read key (row l31)
    const int vkey = (l31 ^ (l31 >> 3)) & 7;         // V read key (row l31)

    const long gbase = (long)bh * S_LEN * DHEAD;
    const float* Qh = Q + gbase;
    const float* Kh = K + gbase;
    const float* Vh = V + gbase;

    const int q0 = qt * 128 + w * 32;               // this wave's 32 q-rows
    const float csq  = rsqrtf((float)dkp[0]) * 1.44269504088896f;
    const float mfac = -1e9f * 1.44269504088896f;
    const bool use_mask = (maskflag[0] != 0);

    __shared__ __align__(16) _Float16 KT[4][TILE_HALFS];   // 32 KB (4-ring)
    __shared__ __align__(16) _Float16 VT[4][TILE_HALFS];   // 32 KB (4-ring)

    // ---- Q B-operand frags, pre-scaled (lane -> Q[q0+l31][ks*16+8h+j]) ----
    half8 qf[4];
    #pragma unroll
    for (int ks = 0; ks < 4; ++ks) {
        const float4* src = (const float4*)(Qh + (long)(q0 + l31) * DHEAD + ks * 16 + h * 8);
        float4 a = src[0], b = src[1];
        union { unsigned u[4]; half8 h8; } u;
        u.u[0] = pk2u(a.x * csq, a.y * csq);
        u.u[1] = pk2u(a.z * csq, a.w * csq);
        u.u[2] = pk2u(b.x * csq, b.y * csq);
        u.u[3] = pk2u(b.z * csq, b.w * csq);
        qf[ks] = u.h8;
    }

    // ---- staging roles (r10-verified layouts) ----
    const int kr  = tid >> 2;            // K row 0..63
    const int ks4 = tid & 3;             // K 16-float segment
    const int vrp = tid >> 3;            // V row-pair 0..31
    const int vdq = tid & 7;             // V d-octet 0..7
    const float* Kb = Kh + (long)kr * DHEAD + ks4 * 16;
    const float* Vb = Vh + (long)(2 * vrp) * DHEAD + vdq * 8;
    const int kcol0 = (((2 * ks4)     ^ (kr & 7)) << 3);
    const int kcol1 = (((2 * ks4 + 1) ^ (kr & 7)) << 3);
    const int vd0   = vdq * 8;
    const int voct  = vrp >> 2;          // V row-octet
    const int vlow  = (2 * vrp) & 7;     // position within chunk

    float4 kf[4], vf[4];
    auto load_tile = [&](int kt) {
        const float4* kp  = (const float4*)(Kb + (long)kt * TILE_HALFS);
        kf[0] = kp[0]; kf[1] = kp[1]; kf[2] = kp[2]; kf[3] = kp[3];
        const float4* vp0 = (const float4*)(Vb + (long)kt * TILE_HALFS);
        const float4* vp1 = (const float4*)(Vb + (long)kt * TILE_HALFS + DHEAD);
        vf[0] = vp0[0]; vf[1] = vp0[1]; vf[2] = vp1[0]; vf[3] = vp1[1];
    };
    auto store_tile = [&](int bb) {
        union { unsigned u[4]; half8 h8; } u0, u1;
        u0.u[0] = pk2u(kf[0].x, kf[0].y);
        u0.u[1] = pk2u(kf[0].z, kf[0].w);
        u0.u[2] = pk2u(kf[1].x, kf[1].y);
        u0.u[3] = pk2u(kf[1].z, kf[1].w);
        u1.u[0] = pk2u(kf[2].x, kf[2].y);
        u1.u[1] = pk2u(kf[2].z, kf[2].w);
        u1.u[2] = pk2u(kf[3].x, kf[3].y);
        u1.u[3] = pk2u(kf[3].z, kf[3].w);
        *(half8*)&KT[bb][kr * 64 + kcol0] = u0.h8;
        *(half8*)&KT[bb][kr * 64 + kcol1] = u1.h8;
        _Float16* vt = &VT[bb][0];
        #define VCOL(j) ((((voct ^ (j) ^ vdq) & 7) << 3) + vlow)
        *(pk16x2*)&vt[(vd0 + 0) * 64 + VCOL(0)] = __builtin_amdgcn_cvt_pkrtz(vf[0].x, vf[2].x);
        *(pk16x2*)&vt[(vd0 + 1) * 64 + VCOL(1)] = __builtin_amdgcn_cvt_pkrtz(vf[0].y, vf[2].y);
        *(pk16x2*)&vt[(vd0 + 2) * 64 + VCOL(2)] = __builtin_amdgcn_cvt_pkrtz(vf[0].z, vf[2].z);
        *(pk16x2*)&vt[(vd0 + 3) * 64 + VCOL(3)] = __builtin_amdgcn_cvt_pkrtz(vf[0].w, vf[2].w);
        *(pk16x2*)&vt[(vd0 + 4) * 64 + VCOL(4)] = __builtin_amdgcn_cvt_pkrtz(vf[1].x, vf[3].x);
        *(pk16x2*)&vt[(vd0 + 5) * 64 + VCOL(5)] = __builtin_amdgcn_cvt_pkrtz(vf[1].y, vf[3].y);
        *(pk16x2*)&vt[(vd0 + 6) * 64 + VCOL(6)] = __builtin_amdgcn_cvt_pkrtz(vf[1].z, vf[3].z);
        *(pk16x2*)&vt[(vd0 + 7) * 64 + VCOL(7)] = __builtin_amdgcn_cvt_pkrtz(vf[1].w, vf[3].w);
        #undef VCOL
    };

    f32x16 o0 = {0.f,0.f,0.f,0.f,0.f,0.f,0.f,0.f,0.f,0.f,0.f,0.f,0.f,0.f,0.f,0.f};
    f32x16 o1 = o0;
    float m_i = -INFINITY;
    float l_i = 0.0f;

    // ---- per-tile bodies, byte-identical math to r10 ----
    auto qk = [&](int bb, f32x16& sa, f32x16& sb) {
        __builtin_amdgcn_s_setprio(1);
        #pragma unroll
        for (int ks = 0; ks < 4; ++ks) {
            const int off = (((2 * ks + h) ^ cx) << 3);
            half8 a0 = *(const half8*)&KT[bb][(l31 << 6) + off];
            half8 a1 = *(const half8*)&KT[bb][2048 + (l31 << 6) + off];
            sa = MFMA32(a0, qf[ks], sa);
            sb = MFMA32(a1, qf[ks], sb);
        }
        __builtin_amdgcn_s_setprio(0);
    };
    auto addmask = [&](int kt, f32x16& sa, f32x16& sb) {
        const float* mrow = mask + (long)(q0 + l31) * S_LEN + kt * BK;
        #pragma unroll
        for (int r = 0; r < 16; ++r) {
            const int k = (r & 3) + ((r >> 2) << 3) + (h << 2);
            sa[r] += mfac * mrow[k];
            sb[r] += mfac * mrow[32 + k];
        }
    };
    auto softmax = [&](f32x16& sa, f32x16& sb) {
        float tt[8];
        #pragma unroll
        for (int i = 0; i < 8; ++i)
            tt[i] = fmaxf(fmaxf(sa[2*i], sa[2*i+1]), fmaxf(sb[2*i], sb[2*i+1]));
        float mx = fmaxf(fmaxf(fmaxf(tt[0], tt[1]), fmaxf(tt[2], tt[3])),
                         fmaxf(fmaxf(tt[4], tt[5]), fmaxf(tt[6], tt[7])));
        mx = xmax32(mx);                               // VALU, not DS
        const bool need = __any(mx > m_i + 8.0f);      // wave-uniform
        const float mnew = need ? fmaxf(m_i, mx) : m_i;
        float ra = 0.f, rb = 0.f;
        #pragma unroll
        for (int r = 0; r < 16; ++r) {
            float p0 = __builtin_amdgcn_exp2f(sa[r] - mnew);
            float p1 = __builtin_amdgcn_exp2f(sb[r] - mnew);
            sa[r] = p0; sb[r] = p1;
            ra += p0; rb += p1;
        }
        float rsum = xadd32(ra + rb);
        if (need) {
            const float alpha = __builtin_amdgcn_exp2f(m_i - mnew);
            #pragma unroll
            for (int r = 0; r < 16; ++r) {
                const int qr = (r & 3) + ((r >> 2) << 3) + (h << 2);
                float a_r = __shfl(alpha, qr, 64);
                o0[r] *= a_r; o1[r] *= a_r;
            }
            l_i = alpha * l_i + rsum;
            m_i = mnew;
        } else {
            l_i += rsum;
        }
    };
    auto pv = [&](int bb, const f32x16& sa, const f32x16& sb) {
        unsigned wp[16];
        #pragma unroll
        for (int d = 0; d < 8; ++d) {
            wp[d]     = pk2u(sa[2*d], sa[2*d+1]);
            wp[8 + d] = pk2u(sb[2*d], sb[2*d+1]);
        }
        __builtin_amdgcn_s_setprio(1);
        #pragma unroll
        for (int si = 0; si < 4; ++si) {
            const int bs = (si >> 1) * 8 + (si & 1) * 4;
            uint2v r0 = pls(wp[bs + 0], wp[bs + 2]);
            uint2v r1 = pls(wp[bs + 1], wp[bs + 3]);
            union { unsigned u[4]; half8 h8; } pa;
            pa.u[0] = r0.x; pa.u[1] = r1.x; pa.u[2] = r0.y; pa.u[3] = r1.y;
            const int voff = (((2 * si + h) ^ vkey) << 3);
            half8 v0 = *(const half8*)&VT[bb][(l31 << 6) + voff];
            half8 v1 = *(const half8*)&VT[bb][2048 + (l31 << 6) + (voff ^ 32)];
            o0 = MFMA32(pa.h8, v0, o0);
            o1 = MFMA32(pa.h8, v1, o1);
        }
        __builtin_amdgcn_s_setprio(0);
    };

    // ---- prologue: stage tiles 0,1 into ring slots 0,1 ----
    load_tile(0); store_tile(0);
    load_tile(1); store_tile(1);
    __syncthreads();

    for (int kt = 0; kt < NT; kt += 2) {
        const int b0 = kt & 3, b1 = (kt + 1) & 3;

        // ---- tile kt ----
        if (kt + 2 < NT) load_tile(kt + 2);
        f32x16 s0 = {0.f,0.f,0.f,0.f,0.f,0.f,0.f,0.f,0.f,0.f,0.f,0.f,0.f,0.f,0.f,0.f};
        f32x16 s1 = s0;
        qk(b0, s0, s1);
        if (kt + 2 < NT) store_tile((kt + 2) & 3);   // staging regs die here
        if (use_mask) addmask(kt, s0, s1);
        softmax(s0, s1);
        pv(b0, s0, s1);

        // ---- tile kt+1 ----
        if (kt + 3 < NT) load_tile(kt + 3);
        f32x16 s2 = {0.f,0.f,0.f,0.f,0.f,0.f,0.f,0.f,0.f,0.f,0.f,0.f,0.f,0.f,0.f,0.f};
        f32x16 s3 = s2;
        qk(b1, s2, s3);
        if (kt + 3 < NT) store_tile((kt + 3) & 3);
        if (use_mask) addmask(kt + 1, s2, s3);
        softmax(s2, s3);
        pv(b1, s2, s3);

        if (kt + 2 < NT) __syncthreads();    // ONE barrier per tile pair
    }

    // ---- epilogue: O /= l (lane qr owns row qr's l) ----
    float* dst = O + gbase;
    #pragma unroll
    for (int r = 0; r < 16; ++r) {
        const int qr = (r & 3) + ((r >> 2) << 3) + (h << 2);
        float lq = __shfl(l_i, qr, 64);
        float inv = __builtin_amdgcn_rcpf(lq);
        const long row = (long)(q0 + qr) * DHEAD;
        dst[row + l31]      = o0[r] * inv;
        dst[row + 32 + l31] = o1[r] * inv;
    }
}

extern "C" void kernel_launch(void* const* d_in, const int* in_sizes, int n_in,
                              void* d_out, int out_size, void* d_ws, size_t ws_size,
                              hipStream_t stream) {
    const float* Q    = (const float*)d_in[0];
    const float* K    = (const float*)d_in[1];
    const float* V    = (const float*)d_in[2];
    const int*   dk   = (const int*)d_in[3];
    const float* mask = (const float*)d_in[4];
    float* out = (float*)d_out;
    int* flag = (int*)d_ws;

    (void)hipMemsetAsync(flag, 0, sizeof(int), stream);
    mask_flag_kernel<<<2048, 256, 0, stream>>>((const float4*)mask, flag);

    attn32r_kernel<<<512, 256, 0, stream>>>(Q, K, V, dk, mask, flag, out);
}

// Round 14
// 238.398 us; speedup vs baseline: 1.0555x; 1.0351x over previous
//
#include <hip/hip_runtime.h>

#define S_LEN 4096
#define DHEAD 64
#define BK    64       // K/V rows per tile
#define NT    (S_LEN / BK)
#define TILE_HALFS (BK * DHEAD)   // 4096 halfs / floats per tile

typedef __fp16   pk16x2 __attribute__((ext_vector_type(2)));
typedef _Float16 half8  __attribute__((ext_vector_type(8)));
typedef float    f32x16 __attribute__((ext_vector_type(16)));
typedef unsigned uint2v __attribute__((ext_vector_type(2)));

#define MFMA32(a, b, c) __builtin_amdgcn_mfma_f32_32x32x16_f16(a, b, c, 0, 0, 0)

__device__ __forceinline__ unsigned pk2u(float a, float b) {
    union { pk16x2 p; unsigned u; } x;
    x.p = __builtin_amdgcn_cvt_pkrtz(a, b);
    return x.u;
}

// permlane32_swap(x,y): r.x[l] = l<32 ? x[l] : y[l-32] ; r.y[l] = l<32 ? x[l+32] : y[l]
__device__ __forceinline__ uint2v pls(unsigned x, unsigned y) {
    return __builtin_amdgcn_permlane32_swap(x, y, false, false);
}
__device__ __forceinline__ float xmax32(float v) {
    uint2v r = pls(__float_as_uint(v), __float_as_uint(v));
    return fmaxf(__uint_as_float(r.x), __uint_as_float(r.y));
}
__device__ __forceinline__ float xadd32(float v) {
    uint2v r = pls(__float_as_uint(v), __float_as_uint(v));
    return __uint_as_float(r.x) + __uint_as_float(r.y);
}

// ---------------------------------------------------------------------------
// Pass 1: is the mask anywhere nonzero? 2048x256 threads, 8 float4/thread.
// ---------------------------------------------------------------------------
__global__ void mask_flag_kernel(const float4* __restrict__ mask, int* __restrict__ flag) {
    const long stride = 2048L * 256;
    long i = (long)blockIdx.x * 256 + threadIdx.x;
    int nz = 0;
    #pragma unroll
    for (int it = 0; it < 8; ++it) {
        float4 a = mask[i + it * stride];
        nz |= (a.x != 0.f) | (a.y != 0.f) | (a.z != 0.f) | (a.w != 0.f);
    }
    if (__any(nz)) {
        if ((threadIdx.x & 63) == 0) atomicOr(flag, 1);
    }
}

// ---------------------------------------------------------------------------
// Pass 2: flash attention. SESSION CHAMPION (round 10, 240.3 us total,
// attn 135.9 us): r9 frame (256 thr, 4 waves x 32 q-rows, inline fp32
// staging, LDS dbuf, one barrier/tile, 2 blocks/CU) + 32x32 inner loop:
// S^T = K.Q^T (lane owns one q-column), P redistributed to the PV A-operand
// fully in-register via permlane32_swap -- NO P LDS round-trip. THR=8
// defer-max; s_setprio around MFMA clusters; XCD-chunked block decode
// (each XCD touches only 2 bh -> K/V L2-resident, FETCH 24.6 MB).
// Falsified alternatives (do not revisit): BQ=64 TLP (r1), 512-thr in-block
// split (r6/r8), conv pre-pass (r1-r3), grid-barrier fusion (r4-r5),
// joint-softmax pair (r11), pair-barrier 4-ring (r13).
//   KT[r][chunk c] = K[r][8*(c ^ (r&7)) .. +8]
//   VT[d][chunk c] = V[8*(c ^ (d&7) ^ ((d>>3)&7)) + j][d]
// ---------------------------------------------------------------------------
__global__ __launch_bounds__(256, 2) void attn32s_kernel(
    const float* __restrict__ Q, const float* __restrict__ K,
    const float* __restrict__ V, const int* __restrict__ dkp,
    const float* __restrict__ mask, const int* __restrict__ maskflag,
    float* __restrict__ O)
{
    const int bid = blockIdx.x;
    const int L   = (bid & 7) * 64 + (bid >> 3);   // XCD-chunked decode, 512 blocks
    const int bh  = L >> 5;                         // 0..15
    const int qt  = L & 31;                         // 0..31

    const int tid  = threadIdx.x;
    const int w    = tid >> 6;          // wave 0..3
    const int lane = tid & 63;
    const int l31  = lane & 31;
    const int h    = lane >> 5;
    const int cx   = lane & 7;                       // K read key (row l31)
    const int vkey = (l31 ^ (l31 >> 3)) & 7;         // V read key (row l31)

    const long gbase = (long)bh * S_LEN * DHEAD;
    const float* Qh = Q + gbase;
    const float* Kh = K + gbase;
    const float* Vh = V + gbase;

    const int q0 = qt * 128 + w * 32;               // this wave's 32 q-rows
    const float csq  = rsqrtf((float)dkp[0]) * 1.44269504088896f;
    const float mfac = -1e9f * 1.44269504088896f;
    const bool use_mask = (maskflag[0] != 0);

    __shared__ __align__(16) _Float16 KT[2][TILE_HALFS];   // 16 KB
    __shared__ __align__(16) _Float16 VT[2][TILE_HALFS];   // 16 KB

    // ---- Q B-operand frags, pre-scaled (lane -> Q[q0+l31][ks*16+8h+j]) ----
    half8 qf[4];
    #pragma unroll
    for (int ks = 0; ks < 4; ++ks) {
        const float4* src = (const float4*)(Qh + (long)(q0 + l31) * DHEAD + ks * 16 + h * 8);
        float4 a = src[0], b = src[1];
        union { unsigned u[4]; half8 h8; } u;
        u.u[0] = pk2u(a.x * csq, a.y * csq);
        u.u[1] = pk2u(a.z * csq, a.w * csq);
        u.u[2] = pk2u(b.x * csq, b.y * csq);
        u.u[3] = pk2u(b.z * csq, b.w * csq);
        qf[ks] = u.h8;
    }

    // ---- staging roles (r8-verified layouts) ----
    const int kr  = tid >> 2;            // K row 0..63
    const int ks4 = tid & 3;             // K 16-float segment
    const int vrp = tid >> 3;            // V row-pair 0..31
    const int vdq = tid & 7;             // V d-octet 0..7
    const float* Kb = Kh + (long)kr * DHEAD + ks4 * 16;
    const float* Vb = Vh + (long)(2 * vrp) * DHEAD + vdq * 8;
    const int kcol0 = (((2 * ks4)     ^ (kr & 7)) << 3);
    const int kcol1 = (((2 * ks4 + 1) ^ (kr & 7)) << 3);
    const int vd0   = vdq * 8;
    const int voct  = vrp >> 2;          // V row-octet
    const int vlow  = (2 * vrp) & 7;     // position within chunk

    float4 kf[4], vf[4];
    auto load_tile = [&](int kt) {
        const float4* kp  = (const float4*)(Kb + (long)kt * TILE_HALFS);
        kf[0] = kp[0]; kf[1] = kp[1]; kf[2] = kp[2]; kf[3] = kp[3];
        const float4* vp0 = (const float4*)(Vb + (long)kt * TILE_HALFS);
        const float4* vp1 = (const float4*)(Vb + (long)kt * TILE_HALFS + DHEAD);
        vf[0] = vp0[0]; vf[1] = vp0[1]; vf[2] = vp1[0]; vf[3] = vp1[1];
    };
    auto store_tile = [&](int bb) {
        union { unsigned u[4]; half8 h8; } u0, u1;
        u0.u[0] = pk2u(kf[0].x, kf[0].y);
        u0.u[1] = pk2u(kf[0].z, kf[0].w);
        u0.u[2] = pk2u(kf[1].x, kf[1].y);
        u0.u[3] = pk2u(kf[1].z, kf[1].w);
        u1.u[0] = pk2u(kf[2].x, kf[2].y);
        u1.u[1] = pk2u(kf[2].z, kf[2].w);
        u1.u[2] = pk2u(kf[3].x, kf[3].y);
        u1.u[3] = pk2u(kf[3].z, kf[3].w);
        *(half8*)&KT[bb][kr * 64 + kcol0] = u0.h8;
        *(half8*)&KT[bb][kr * 64 + kcol1] = u1.h8;
        _Float16* vt = &VT[bb][0];
        #define VCOL(j) ((((voct ^ (j) ^ vdq) & 7) << 3) + vlow)
        *(pk16x2*)&vt[(vd0 + 0) * 64 + VCOL(0)] = __builtin_amdgcn_cvt_pkrtz(vf[0].x, vf[2].x);
        *(pk16x2*)&vt[(vd0 + 1) * 64 + VCOL(1)] = __builtin_amdgcn_cvt_pkrtz(vf[0].y, vf[2].y);
        *(pk16x2*)&vt[(vd0 + 2) * 64 + VCOL(2)] = __builtin_amdgcn_cvt_pkrtz(vf[0].z, vf[2].z);
        *(pk16x2*)&vt[(vd0 + 3) * 64 + VCOL(3)] = __builtin_amdgcn_cvt_pkrtz(vf[0].w, vf[2].w);
        *(pk16x2*)&vt[(vd0 + 4) * 64 + VCOL(4)] = __builtin_amdgcn_cvt_pkrtz(vf[1].x, vf[3].x);
        *(pk16x2*)&vt[(vd0 + 5) * 64 + VCOL(5)] = __builtin_amdgcn_cvt_pkrtz(vf[1].y, vf[3].y);
        *(pk16x2*)&vt[(vd0 + 6) * 64 + VCOL(6)] = __builtin_amdgcn_cvt_pkrtz(vf[1].z, vf[3].z);
        *(pk16x2*)&vt[(vd0 + 7) * 64 + VCOL(7)] = __builtin_amdgcn_cvt_pkrtz(vf[1].w, vf[3].w);
        #undef VCOL
    };

    f32x16 o0 = {0.f,0.f,0.f,0.f,0.f,0.f,0.f,0.f,0.f,0.f,0.f,0.f,0.f,0.f,0.f,0.f};
    f32x16 o1 = o0;
    float m_i = -INFINITY;
    float l_i = 0.0f;

    load_tile(0);
    store_tile(0);
    __syncthreads();

    for (int kt = 0; kt < NT; ++kt) {
        const int b = kt & 1;
        if (kt + 1 < NT) load_tile(kt + 1);   // issue global prefetch

        // ---- S^T = K . Q^T : s0 = k-rows 0..31, s1 = k-rows 32..63 ----
        f32x16 s0 = {0.f,0.f,0.f,0.f,0.f,0.f,0.f,0.f,0.f,0.f,0.f,0.f,0.f,0.f,0.f,0.f};
        f32x16 s1 = s0;
        __builtin_amdgcn_s_setprio(1);
        #pragma unroll
        for (int ks = 0; ks < 4; ++ks) {
            const int off = (((2 * ks + h) ^ cx) << 3);
            half8 a0 = *(const half8*)&KT[b][(l31 << 6) + off];
            half8 a1 = *(const half8*)&KT[b][2048 + (l31 << 6) + off];
            s0 = MFMA32(a0, qf[ks], s0);
            s1 = MFMA32(a1, qf[ks], s1);
        }
        __builtin_amdgcn_s_setprio(0);

        // ---- stage next tile NOW (r8-verified placement): staging regs die
        // before softmax/PV; buffer b^1 unread during kt; barrier publishes.
        if (kt + 1 < NT) store_tile(b ^ 1);

        if (use_mask) {
            const float* mrow = mask + (long)(q0 + l31) * S_LEN + kt * BK;
            #pragma unroll
            for (int r = 0; r < 16; ++r) {
                const int k = (r & 3) + ((r >> 2) << 3) + (h << 2);
                s0[r] += mfac * mrow[k];
                s1[r] += mfac * mrow[32 + k];
            }
        }

        // ---- online softmax (exp2 domain), THR=8 defer-max ----
        {
            float tt[8];
            #pragma unroll
            for (int i = 0; i < 8; ++i)
                tt[i] = fmaxf(fmaxf(s0[2*i], s0[2*i+1]), fmaxf(s1[2*i], s1[2*i+1]));
            float mx = fmaxf(fmaxf(fmaxf(tt[0], tt[1]), fmaxf(tt[2], tt[3])),
                             fmaxf(fmaxf(tt[4], tt[5]), fmaxf(tt[6], tt[7])));
            mx = xmax32(mx);                               // VALU, not DS
            const bool need = __any(mx > m_i + 8.0f);      // wave-uniform
            const float mnew = need ? fmaxf(m_i, mx) : m_i;
            float ra = 0.f, rb = 0.f;
            #pragma unroll
            for (int r = 0; r < 16; ++r) {
                float p0 = __builtin_amdgcn_exp2f(s0[r] - mnew);
                float p1 = __builtin_amdgcn_exp2f(s1[r] - mnew);
                s0[r] = p0; s1[r] = p1;
                ra += p0; rb += p1;
            }
            float rsum = xadd32(ra + rb);
            if (need) {
                const float alpha = __builtin_amdgcn_exp2f(m_i - mnew);
                #pragma unroll
                for (int r = 0; r < 16; ++r) {
                    const int qr = (r & 3) + ((r >> 2) << 3) + (h << 2);
                    float a_r = __shfl(alpha, qr, 64);
                    o0[r] *= a_r; o1[r] *= a_r;
                }
                l_i = alpha * l_i + rsum;
                m_i = mnew;
            } else {
                l_i += rsum;
            }
        }

        // ---- P words -> PV A-operand fully in-register (pls direct) ----
        unsigned wp[16];
        #pragma unroll
        for (int d = 0; d < 8; ++d) {
            wp[d]     = pk2u(s0[2*d], s0[2*d+1]);
            wp[8 + d] = pk2u(s1[2*d], s1[2*d+1]);
        }

        __builtin_amdgcn_s_setprio(1);
        #pragma unroll
        for (int si = 0; si < 4; ++si) {
            const int bs = (si >> 1) * 8 + (si & 1) * 4;
            uint2v r0 = pls(wp[bs + 0], wp[bs + 2]);
            uint2v r1 = pls(wp[bs + 1], wp[bs + 3]);
            union { unsigned u[4]; half8 h8; } pa;
            pa.u[0] = r0.x; pa.u[1] = r1.x; pa.u[2] = r0.y; pa.u[3] = r1.y;
            const int voff = (((2 * si + h) ^ vkey) << 3);
            half8 v0 = *(const half8*)&VT[b][(l31 << 6) + voff];
            half8 v1 = *(const half8*)&VT[b][2048 + (l31 << 6) + (voff ^ 32)];
            o0 = MFMA32(pa.h8, v0, o0);
            o1 = MFMA32(pa.h8, v1, o1);
        }
        __builtin_amdgcn_s_setprio(0);

        if (kt + 1 < NT) __syncthreads();    // publish b^1 for next iteration
    }

    // ---- epilogue: O /= l (lane qr owns row qr's l) ----
    float* dst = O + gbase;
    #pragma unroll
    for (int r = 0; r < 16; ++r) {
        const int qr = (r & 3) + ((r >> 2) << 3) + (h << 2);
        float lq = __shfl(l_i, qr, 64);
        float inv = __builtin_amdgcn_rcpf(lq);
        const long row = (long)(q0 + qr) * DHEAD;
        dst[row + l31]      = o0[r] * inv;
        dst[row + 32 + l31] = o1[r] * inv;
    }
}

extern "C" void kernel_launch(void* const* d_in, const int* in_sizes, int n_in,
                              void* d_out, int out_size, void* d_ws, size_t ws_size,
                              hipStream_t stream) {
    const float* Q    = (const float*)d_in[0];
    const float* K    = (const float*)d_in[1];
    const float* V    = (const float*)d_in[2];
    const int*   dk   = (const int*)d_in[3];
    const float* mask = (const float*)d_in[4];
    float* out = (float*)d_out;
    int* flag = (int*)d_ws;

    (void)hipMemsetAsync(flag, 0, sizeof(int), stream);
    mask_flag_kernel<<<2048, 256, 0, stream>>>((const float4*)mask, flag);

    attn32s_kernel<<<512, 256, 0, stream>>>(Q, K, V, dk, mask, flag, out);
}